// Round 13
// baseline (336.162 us; speedup 1.0000x reference)
//
#include <hip/hip_runtime.h>
#include <hip/hip_bf16.h>

#define DI __device__ __forceinline__

typedef __attribute__((ext_vector_type(4))) float f32x4;
typedef __attribute__((ext_vector_type(8))) short bf16x8;
typedef __attribute__((ext_vector_type(4))) short bf16x4;

static constexpr int CB = 16;        // batch
static constexpr int CC = 384;       // channels
static constexpr int CH = 28, CW = 28;
static constexpr int CD = 48;        // head dim
static constexpr int CN = 785;       // 1 + 28*28
static constexpr int CM = CB * CN;   // 12560 rows
static constexpr int C3 = 3 * CC;    // 1152
static constexpr int CF = 4 * CC;    // 1536
static constexpr int HW = CH * CW;   // 784
static constexpr int NP = 832;       // padded seq for vt

DI short f2b(float f) {
  __hip_bfloat16 h = __float2bfloat16(f);
  return *reinterpret_cast<short*>(&h);
}
DI float b2f(short s) {
  union { unsigned u; float f; } x;
  x.u = ((unsigned)(unsigned short)s) << 16;
  return x.f;
}

DI void gload16(const short* g, short* l) {
  __builtin_amdgcn_global_load_lds((const __attribute__((address_space(1))) void*)g,
                                   (__attribute__((address_space(3))) void*)l, 16, 0, 0);
}

// ---------------------------------------------------------------------------
// K0: zero global_attn, write cls row of xc
// ---------------------------------------------------------------------------
__global__ void k_misc(const float* __restrict__ cls, float* __restrict__ xc,
                       float* __restrict__ ga) {
  const int gid = blockIdx.x * 256 + threadIdx.x;
  if (gid < CB * HW) ga[gid] = 0.f;
  if (gid < CB * CC) {
    const int b = gid / CC, c = gid % CC;
    xc[((size_t)b * CN) * CC + c] = cls[gid];
  }
}

// ---------------------------------------------------------------------------
// K0b: convert the four weight matrices fp32 -> bf16 (contiguous in wbuf)
// ---------------------------------------------------------------------------
__global__ void k_wconv(const float* __restrict__ s0, const float* __restrict__ s1,
                        const float* __restrict__ s2, const float* __restrict__ s3,
                        short* __restrict__ dst) {
  const int gid = (blockIdx.x * 256 + threadIdx.x) * 4;
  if (gid >= 1769472) return;
  const float* s; int off;
  if (gid < 442368)       { s = s0; off = gid; }
  else if (gid < 589824)  { s = s1; off = gid - 442368; }
  else if (gid < 1179648) { s = s2; off = gid - 589824; }
  else                    { s = s3; off = gid - 1179648; }
  f32x4 v = *(const f32x4*)(s + off);
  bf16x4 o;
#pragma unroll
  for (int i = 0; i < 4; i++) o[i] = f2b(v[i]);
  *(bf16x4*)(dst + gid) = o;
}

// ---------------------------------------------------------------------------
// K1: depthwise conv3x3 + residual, coalesced along hw, LDS-transposed write.
// ---------------------------------------------------------------------------
__global__ __launch_bounds__(256) void k_conv_t(const float* __restrict__ x,
                                                const float* __restrict__ cw,
                                                const float* __restrict__ cb,
                                                float* __restrict__ xc) {
  __shared__ float T[64][65];
  __shared__ float Wc[64 * 9];
  __shared__ float Cbs[64];
  const int b = blockIdx.z;
  const int cc = blockIdx.y * 64;
  const int hw0 = blockIdx.x * 64;
  const int t = threadIdx.x;
  const int hwi = t & 63, ci0 = t >> 6;
  const int hw = hw0 + hwi;
  const int yy = hw / CW, xx = hw % CW;
  const int ci2 = t & 63, hb2 = t >> 6;

  for (int i = t; i < 64 * 9; i += 256) Wc[i] = cw[cc * 9 + i];
  if (t < 64) Cbs[t] = cb[cc + t];
  __syncthreads();
  if (hw < HW) {
    const int ctr = yy * CW + xx;
    int off9[9]; float mk9[9];
#pragma unroll
    for (int ky = 0; ky < 3; ky++)
#pragma unroll
      for (int kx = 0; kx < 3; kx++) {
        const int iy = yy + ky - 1, ix = xx + kx - 1;
        const bool v = (iy >= 0 && iy < CH && ix >= 0 && ix < CW);
        off9[ky * 3 + kx] = v ? iy * CW + ix : ctr;
        mk9[ky * 3 + kx] = v ? 1.f : 0.f;
      }
#pragma unroll
    for (int j = 0; j < 16; j += 2) {
      const int cl0 = ci0 * 16 + j;
      const float* xp0 = x + ((size_t)(b * CC + cc + cl0)) * HW;
      const float* xp1 = xp0 + HW;
      float t0[9], t1[9];
#pragma unroll
      for (int q = 0; q < 9; q++) { t0[q] = xp0[off9[q]]; t1[q] = xp1[off9[q]]; }
      const float c0 = xp0[ctr], c1 = xp1[ctr];
      float a0 = Cbs[cl0], a1 = Cbs[cl0 + 1];
#pragma unroll
      for (int q = 0; q < 9; q++) {
        a0 += Wc[cl0 * 9 + q] * (t0[q] * mk9[q]);
        a1 += Wc[(cl0 + 1) * 9 + q] * (t1[q] * mk9[q]);
      }
      T[cl0][hwi] = c0 + a0;
      T[cl0 + 1][hwi] = c1 + a1;
    }
  }
  __syncthreads();
#pragma unroll
  for (int j = 0; j < 16; j++) {
    const int hwl = hb2 + j * 4;
    if (hw0 + hwl < HW)
      xc[((size_t)b * CN + 1 + hw0 + hwl) * CC + cc + ci2] = T[ci2][hwl];
  }
}

// ---------------------------------------------------------------------------
// K2: LayerNorm over last dim (384), fp32 in -> bf16 out. 1 wave per row.
// ---------------------------------------------------------------------------
__global__ __launch_bounds__(256) void k_ln(const float* __restrict__ xin,
                                            const float* __restrict__ g,
                                            const float* __restrict__ bta,
                                            short* __restrict__ y, int Mtot) {
  const int row = blockIdx.x * 4 + (threadIdx.x >> 6);
  const int l = threadIdx.x & 63;
  if (row >= Mtot) return;
  const float* xr = xin + (size_t)row * CC;
  float v[6], s = 0.f, ss = 0.f;
#pragma unroll
  for (int i = 0; i < 6; i++) {
    v[i] = xr[l + i * 64];
    s += v[i];
    ss += v[i] * v[i];
  }
#pragma unroll
  for (int m = 1; m < 64; m <<= 1) { s += __shfl_xor(s, m); ss += __shfl_xor(ss, m); }
  const float mu = s * (1.f / CC);
  const float var = ss * (1.f / CC) - mu * mu;
  const float r = rsqrtf(var + 1e-5f);
#pragma unroll
  for (int i = 0; i < 6; i++) {
    const int c = l + i * 64;
    y[(size_t)row * CC + c] = f2b((v[i] - mu) * r * g[c] + bta[c]);
  }
}

// ---------------------------------------------------------------------------
// K3: GEMM  C[M,N] = A[M,K] @ W[N,K]^T (+bias)(+gelu)(+resid)
//     2-buffer pipelined + XCD-chunked N-fastest grid swizzle (round-12 best).
// ---------------------------------------------------------------------------
template <int BM, int DOGELU, int DORES, int DOBIAS, int OUTBF>
__global__ __launch_bounds__(256) void k_gemm(const short* __restrict__ A,
                                              const short* __restrict__ W,
                                              const float* __restrict__ bias,
                                              const float* __restrict__ resid,
                                              void* __restrict__ out_,
                                              int M, int N, int K, int NN) {
  constexpr int MI = BM / 32;
  constexpr int ACALLS = BM / 64;
  constexpr int ASZ = BM * 32, BSZ = 128 * 32;
  __shared__ short As[2 * ASZ];
  __shared__ short Bs[2 * BSZ];

  const int nwg = gridDim.x;
  const int q = nwg >> 3, r = nwg & 7;
  const int x = blockIdx.x & 7, j = blockIdx.x >> 3;
  const int base = (x < r) ? x * (q + 1) : r * (q + 1) + (x - r) * q;
  const int wgid = base + j;
  const int bm = (wgid / NN) * BM, bn = (wgid % NN) * 128;

  const int t = threadIdx.x, w = t >> 6, l = t & 63, g = l >> 4, li = l & 15;
  const int wm = (w >> 1) * (BM / 2), wn = (w & 1) * 64;

  const int srow = l >> 2;
  const int scol = (l & 3) * 8;
  const short* aSrc[ACALLS]; int aOff[ACALLS];
#pragma unroll
  for (int jj = 0; jj < ACALLS; jj++) {
    int arow = bm + w * (BM / 4) + jj * 16 + srow; if (arow > M - 1) arow = M - 1;
    aSrc[jj] = A + (size_t)arow * K + scol;
    aOff[jj] = (w * (BM / 4) + jj * 16) * 32;
  }
  const short* bSrc[2]; int bOff[2];
#pragma unroll
  for (int jj = 0; jj < 2; jj++) {
    const int brow = bn + w * 32 + jj * 16 + srow;
    bSrc[jj] = W + (size_t)brow * K + scol;
    bOff[jj] = (w * 32 + jj * 16) * 32;
  }

  auto stage = [&](int buf, int kt) {
    const int ko = kt * 32;
#pragma unroll
    for (int jj = 0; jj < ACALLS; jj++)
      gload16(aSrc[jj] + ko, &As[buf * ASZ] + aOff[jj]);
#pragma unroll
    for (int jj = 0; jj < 2; jj++)
      gload16(bSrc[jj] + ko, &Bs[buf * BSZ] + bOff[jj]);
  };

  f32x4 acc[MI][4] = {};
  const int nkt = K / 32;
  stage(0, 0);
  __syncthreads();
  int cur = 0;
  for (int kt = 0; kt < nkt; kt++) {
    if (kt + 1 < nkt) stage(cur ^ 1, kt + 1);
    const short* Ab = &As[cur * ASZ];
    const short* Bb = &Bs[cur * BSZ];
    bf16x8 af[MI], bf[4];
#pragma unroll
    for (int mi = 0; mi < MI; mi++)
      af[mi] = *(const bf16x8*)&Ab[(wm + mi * 16 + li) * 32 + g * 8];
#pragma unroll
    for (int ni = 0; ni < 4; ni++)
      bf[ni] = *(const bf16x8*)&Bb[(wn + ni * 16 + li) * 32 + g * 8];
#pragma unroll
    for (int mi = 0; mi < MI; mi++)
#pragma unroll
      for (int ni = 0; ni < 4; ni++)
        acc[mi][ni] = __builtin_amdgcn_mfma_f32_16x16x32_bf16(af[mi], bf[ni], acc[mi][ni], 0, 0, 0);
    __syncthreads();
    cur ^= 1;
  }

#pragma unroll
  for (int mi = 0; mi < MI; mi++)
#pragma unroll
    for (int ni = 0; ni < 4; ni++) {
      const int col = bn + wn + ni * 16 + li;
      float bv = 0.f;
      if constexpr (DOBIAS) bv = bias[col];
#pragma unroll
      for (int rr = 0; rr < 4; rr++) {
        const int row = bm + wm + mi * 16 + g * 4 + rr;
        if (row < M) {
          float v = acc[mi][ni][rr] + bv;
          if constexpr (DOGELU) v = 0.5f * v * (1.f + erff(v * 0.7071067811865475f));
          if constexpr (DORES) v += resid[(size_t)row * N + col];
          if constexpr (OUTBF)
            ((short*)out_)[(size_t)row * N + col] = f2b(v);
          else
            ((float*)out_)[(size_t)row * N + col] = v;
        }
      }
    }
}

// ---------------------------------------------------------------------------
// K3b: pre-transpose V: qkvb[b][n][768 + h*48 + d] -> vt[bh][d][NP=832]
// ---------------------------------------------------------------------------
__global__ __launch_bounds__(256) void k_vt(const short* __restrict__ qkv,
                                            short* __restrict__ vt) {
  __shared__ short Tl[48 * 71];
  const int n0 = blockIdx.x * 64;
  const int bh = blockIdx.y;
  const int b = bh >> 3, h = bh & 7;
  const int t = threadIdx.x;
  const size_t bbase = (size_t)b * CN;
#pragma unroll
  for (int it = 0; it < 2; it++) {
    const int gi = t + it * 256;
    if (gi < 384) {
      const int nrel = gi / 6, dg = gi % 6;
      const int n = n0 + nrel;
      bf16x8 val = {};
      if (n < CN)
        val = *(const bf16x8*)(qkv + (bbase + n) * C3 + 2 * CC + h * CD + dg * 8);
#pragma unroll
      for (int i = 0; i < 8; i++) Tl[(dg * 8 + i) * 71 + nrel] = val[i];
    }
  }
  __syncthreads();
#pragma unroll
  for (int it = 0; it < 2; it++) {
    const int gj = t + it * 256;
    if (gj < 384) {
      const int d = gj >> 3, ng = gj & 7;
      bf16x8 v;
#pragma unroll
      for (int i = 0; i < 8; i++) v[i] = Tl[d * 71 + ng * 8 + i];
      *(bf16x8*)(vt + ((size_t)bh * CD + d) * NP + n0 + ng * 8) = v;
    }
  }
}

// ---------------------------------------------------------------------------
// K4: flash attention v3 — VALU-reduction pass on the round-12 structure:
//     Q pre-scaled by scale*log2e -> exp2 softmax (saves 2 mul/elem);
//     OOB mask hoisted to last tile; defer-max (THR=8, log2 domain);
//     double-buffered LDS with ONE raw barrier/tile (lgkmcnt-only wait ->
//     K/V prefetch spans the barrier); prefetch via incremented pointers.
// ---------------------------------------------------------------------------
__global__ __launch_bounds__(256) void k_attn(const short* __restrict__ qkv,
                                              const short* __restrict__ vt,
                                              short* __restrict__ o) {
  __shared__ short Ks[2][64 * 48];   // [kv][d] rows 96B, XOR-swizzled
  __shared__ short Vs[2][48 * 64];   // [d][kv] rows 128B, XOR-swizzled
  const int f = blockIdx.x;
  const int xslot = f & 7, grp = f >> 3;
  const int bh = xslot + 8 * (grp & 15);
  const int qt = grp >> 4;                 // 0..12
  const int b = bh >> 3, h = bh & 7;
  const int q0 = qt * 64;
  const int t = threadIdx.x, w = t >> 6, l = t & 63, g = l >> 4, li = l & 15;
  const size_t bbase = (size_t)b * CN;

  // Q fragment pre-scaled by 1/sqrt(48) * log2(e)  (exp -> exp2 fold)
  const float SC = 0.14433756729740643f * 1.4426950408889634f;
  const int qrow = q0 + w * 16 + li;
  const int qr = qrow > CN - 1 ? CN - 1 : qrow;
  const short* qb = qkv + (bbase + qr) * C3 + h * CD;
  bf16x8 qf0, qf1 = {};
  {
    bf16x8 q0r = *(const bf16x8*)(qb + g * 8);
#pragma unroll
    for (int i = 0; i < 8; i++) qf0[i] = f2b(b2f(q0r[i]) * SC);
    if (g < 2) {
      bf16x8 q1r = *(const bf16x8*)(qb + 32 + g * 8);
#pragma unroll
      for (int i = 0; i < 8; i++) qf1[i] = f2b(b2f(q1r[i]) * SC);
    }
  }

  float mr = -1e30f, ls = 0.f;
  f32x4 oa[3] = {};

  // staging geometry (per-thread, loop-invariant)
  const int krow0 = t / 6, kcg0 = t % 6;
  const int krow1 = (t + 256) / 6, kcg1 = (t + 256) % 6;   // valid when t<128
  const int vd0 = t >> 3, vkvg0 = t & 7;
  const int vd1 = (t + 256) >> 3, vkvg1 = (t + 256) & 7;   // valid when t<128
  const int ksb0 = (krow0 * 96 + kcg0 * 16) ^ ((krow0 & 7) << 4);
  const int ksb1 = (krow1 * 96 + kcg1 * 16) ^ ((krow1 & 7) << 4);
  const int vsb0 = (vd0 * 128 + vkvg0 * 16) ^ ((vd0 & 7) << 4);
  const int vsb1 = (vd1 * 128 + vkvg1 * 16) ^ ((vd1 & 7) << 4);
  const short* kbase = qkv + bbase * C3 + CC + h * CD;
  const short* vbase = vt + (size_t)bh * CD * NP;
  const short* kp0 = kbase + (size_t)krow0 * C3 + kcg0 * 8;
  const short* kp1 = kbase + (size_t)krow1 * C3 + kcg1 * 8;
  const short* vp0 = vbase + vd0 * NP + vkvg0 * 8;
  const short* vp1 = vbase + vd1 * NP + vkvg1 * 8;

  // prologue: tile 0 -> regs -> buf0; issue tile 1 loads
  bf16x8 kr0, kr1 = {}, vr0, vr1 = {};
  kr0 = *(const bf16x8*)kp0;  vr0 = *(const bf16x8*)vp0;
  if (t < 128) { kr1 = *(const bf16x8*)kp1; vr1 = *(const bf16x8*)vp1; }
  *(bf16x8*)((char*)Ks[0] + ksb0) = kr0;
  *(bf16x8*)((char*)Vs[0] + vsb0) = vr0;
  if (t < 128) {
    *(bf16x8*)((char*)Ks[0] + ksb1) = kr1;
    *(bf16x8*)((char*)Vs[0] + vsb1) = vr1;
  }
  kp0 += 64 * C3; vp0 += 64; kp1 += 64 * C3; vp1 += 64;
  kr0 = *(const bf16x8*)kp0;  vr0 = *(const bf16x8*)vp0;    // tile 1 (kv<=127, no clamp)
  if (t < 128) { kr1 = *(const bf16x8*)kp1; vr1 = *(const bf16x8*)vp1; }
  __syncthreads();

  for (int kt = 0; kt < 13; kt++) {
    const int cur = kt & 1, nxt = cur ^ 1;
    // write tile kt+1 into buf[nxt] (regs from prefetch; vmcnt auto-waited)
    if (kt < 12) {
      *(bf16x8*)((char*)Ks[nxt] + ksb0) = kr0;
      *(bf16x8*)((char*)Vs[nxt] + vsb0) = vr0;
      if (t < 128) {
        *(bf16x8*)((char*)Ks[nxt] + ksb1) = kr1;
        *(bf16x8*)((char*)Vs[nxt] + vsb1) = vr1;
      }
    }
    // issue prefetch of tile kt+2 (pointer-increment; K clamps only at tile 12)
    if (kt + 2 <= 12) {
      kp0 += 64 * C3; vp0 += 64; kp1 += 64 * C3; vp1 += 64;
      if (kt + 2 < 12) {
        kr0 = *(const bf16x8*)kp0; vr0 = *(const bf16x8*)vp0;
        if (t < 128) { kr1 = *(const bf16x8*)kp1; vr1 = *(const bf16x8*)vp1; }
      } else {
        const short* kq0 = (768 + krow0 <= CN - 1) ? kp0
                          : kbase + (size_t)(CN - 1) * C3 + kcg0 * 8;
        kr0 = *(const bf16x8*)kq0; vr0 = *(const bf16x8*)vp0;
        if (t < 128) {
          const short* kq1 = (768 + krow1 <= CN - 1) ? kp1
                            : kbase + (size_t)(CN - 1) * C3 + kcg1 * 8;
          kr1 = *(const bf16x8*)kq1; vr1 = *(const bf16x8*)vp1;
        }
      }
    }

    // ---- S = K Q^T (pre-scaled): s[ni][r] = log2e*scale*logit
    const char* KsC = (const char*)Ks[cur];
    const char* VsC = (const char*)Vs[cur];
    f32x4 s[4];
    __builtin_amdgcn_s_setprio(1);
#pragma unroll
    for (int ni = 0; ni < 4; ni++) {
      const int krw = ni * 16 + li;
      const int sw = (krw & 7) << 4;
      bf16x8 kf0 = *(const bf16x8*)(KsC + ((krw * 96 + g * 16) ^ sw));
      bf16x8 kf1 = {};
      if (g < 2) kf1 = *(const bf16x8*)(KsC + ((krw * 96 + 64 + g * 16) ^ sw));
      f32x4 acc = {};
      acc = __builtin_amdgcn_mfma_f32_16x16x32_bf16(kf0, qf0, acc, 0, 0, 0);
      acc = __builtin_amdgcn_mfma_f32_16x16x32_bf16(kf1, qf1, acc, 0, 0, 0);
      s[ni] = acc;
    }
    __builtin_amdgcn_s_setprio(0);

    // OOB mask only on the last tile (kv 768..831; valid <= 784)
    if (kt == 12) {
#pragma unroll
      for (int ni = 0; ni < 4; ni++)
#pragma unroll
        for (int rr = 0; rr < 4; rr++)
          if (768 + ni * 16 + g * 4 + rr >= CN) s[ni][rr] = -1e30f;
    }

    // row max (per-lane 16 elems, then across g via 2 shfl_xor)
    float mt = s[0][0];
#pragma unroll
    for (int ni = 0; ni < 4; ni++)
#pragma unroll
      for (int rr = 0; rr < 4; rr++) mt = fmaxf(mt, s[ni][rr]);
    mt = fmaxf(mt, __shfl_xor(mt, 16));
    mt = fmaxf(mt, __shfl_xor(mt, 32));

    // defer-max: rescale only if some row grew > 8 (in log2 domain)
    if (!__all(mt - mr <= 8.f)) {
      const float mn = fmaxf(mr, mt);
      const float al = __builtin_exp2f(mr - mn);
      mr = mn;
      ls *= al;
      const int sb = (l & 48) + ((l & 48) >> 2);
      float ar[4];
#pragma unroll
      for (int rr = 0; rr < 4; rr++) ar[rr] = __shfl(al, sb + rr);
#pragma unroll
      for (int d = 0; d < 3; d++)
#pragma unroll
        for (int rr = 0; rr < 4; rr++) oa[d][rr] *= ar[rr];
    }

    float ps = 0.f;
#pragma unroll
    for (int ni = 0; ni < 4; ni++)
#pragma unroll
      for (int rr = 0; rr < 4; rr++) {
        const float p = __builtin_exp2f(s[ni][rr] - mr);
        s[ni][rr] = p;
        ps += p;
      }
    ps += __shfl_xor(ps, 16);
    ps += __shfl_xor(ps, 32);
    ls += ps;

    // pack P per sigma: k=g*8+i -> kv = ks*32 + (i<4 ? g*4+i : 16+g*4+i-4)
    bf16x8 pa[2];
#pragma unroll
    for (int ks = 0; ks < 2; ks++)
#pragma unroll
      for (int i = 0; i < 8; i++)
        pa[ks][i] = f2b(i < 4 ? s[2 * ks][i] : s[2 * ks + 1][i - 4]);

    // O += P V
    __builtin_amdgcn_s_setprio(1);
#pragma unroll
    for (int d = 0; d < 3; d++) {
      const int drow = d * 16 + li;
      const int sw = (drow & 7) << 4;
#pragma unroll
      for (int ks = 0; ks < 2; ks++) {
        bf16x4 lo = *(const bf16x4*)(VsC + ((drow * 128 + ks * 64 + g * 8) ^ sw));
        bf16x4 hi = *(const bf16x4*)(VsC + ((drow * 128 + ks * 64 + 32 + g * 8) ^ sw));
        bf16x8 vb;
#pragma unroll
        for (int i = 0; i < 4; i++) { vb[i] = lo[i]; vb[4 + i] = hi[i]; }
        oa[d] = __builtin_amdgcn_mfma_f32_16x16x32_bf16(pa[ks], vb, oa[d], 0, 0, 0);
      }
    }
    __builtin_amdgcn_s_setprio(0);

    // single barrier per tile: drain LDS ops only; global prefetch stays
    // in flight across the barrier (vmcnt NOT drained)
    asm volatile("s_waitcnt lgkmcnt(0)" ::: "memory");
    __builtin_amdgcn_sched_barrier(0);
    __builtin_amdgcn_s_barrier();
  }

  // epilogue: O[q=g*4+r][d=d*16+li]; ls lives at lane li=q -> shfl
  const int sb = (l & 48) + ((l & 48) >> 2);
  float lr[4];
#pragma unroll
  for (int rr = 0; rr < 4; rr++) lr[rr] = __shfl(ls, sb + rr);
#pragma unroll
  for (int d = 0; d < 3; d++)
#pragma unroll
    for (int rr = 0; rr < 4; rr++) {
      const int n = q0 + w * 16 + g * 4 + rr;
      if (n < CN)
        o[(bbase + n) * CC + h * CD + d * 16 + li] = f2b(oa[d][rr] / lr[rr]);
    }
}

// ---------------------------------------------------------------------------
// K5: global_attn = mean over heads of softmax(q0 . k)[1:]. grid = B*H blocks.
// ---------------------------------------------------------------------------
__global__ __launch_bounds__(256) void k_gattn(const short* __restrict__ qkv,
                                               float* __restrict__ ga) {
  const int b = blockIdx.x >> 3, h = blockIdx.x & 7;
  __shared__ float red[4];
  const int t = threadIdx.x;
  const size_t bbase = (size_t)b * CN;
  const short* q0 = qkv + bbase * C3 + h * CD;
  float qv[CD];
#pragma unroll
  for (int i = 0; i < CD; i++) qv[i] = b2f(q0[i]);
  float lg[4], ev[4];
  float lmax = -1e30f;
#pragma unroll
  for (int j = 0; j < 4; j++) {
    const int m = t + j * 256;
    if (m < CN) {
      const short* kr = qkv + (bbase + m) * C3 + CC + h * CD;
      float acc = 0.f;
#pragma unroll
      for (int i = 0; i < CD; i++) acc += qv[i] * b2f(kr[i]);
      lg[j] = acc * 0.14433756729740643f;
      lmax = fmaxf(lmax, lg[j]);
    } else lg[j] = -1e30f;
  }
  for (int msk = 1; msk < 64; msk <<= 1) lmax = fmaxf(lmax, __shfl_xor(lmax, msk));
  if ((t & 63) == 0) red[t >> 6] = lmax;
  __syncthreads();
  lmax = fmaxf(fmaxf(red[0], red[1]), fmaxf(red[2], red[3]));
  __syncthreads();
  float es = 0.f;
#pragma unroll
  for (int j = 0; j < 4; j++) {
    ev[j] = (t + j * 256 < CN) ? __expf(lg[j] - lmax) : 0.f;
    es += ev[j];
  }
  for (int msk = 1; msk < 64; msk <<= 1) es += __shfl_xor(es, msk);
  if ((t & 63) == 0) red[t >> 6] = es;
  __syncthreads();
  es = red[0] + red[1] + red[2] + red[3];
  const float inv = 0.125f / es;
#pragma unroll
  for (int j = 0; j < 4; j++) {
    const int m = t + j * 256;
    if (m >= 1 && m < CN) atomicAdd(&ga[b * HW + m - 1], ev[j] * inv);
  }
}

// ---------------------------------------------------------------------------
// K6: output: x_out via LDS-tiled transpose (both sides coalesced) + cls_out
// ---------------------------------------------------------------------------
__global__ __launch_bounds__(256) void k_out(const float* __restrict__ xc,
                                             float* __restrict__ outp) {
  const int b = blockIdx.y, tile = blockIdx.x, t = threadIdx.x;
  if (tile == 78) {
    for (int i = t; i < CC; i += 256)
      outp[b * CC + i] = xc[((size_t)b * CN) * CC + i];
    return;
  }
  __shared__ float T[64][65];
  const int ct = tile / 13, ht = tile % 13;
  const int c0 = ct * 64, hw0 = ht * 64;
  const int ci = t & 63, hb = t >> 6;
  for (int j = 0; j < 16; j++) {
    const int hwl = hb + j * 4;
    if (hw0 + hwl < HW)
      T[ci][hwl] = xc[((size_t)b * CN + 1 + hw0 + hwl) * CC + c0 + ci];
  }
  __syncthreads();
  const int hi = t & 63, cb2 = t >> 6;
  float* xo = outp + CB * CC;
  for (int j = 0; j < 16; j++) {
    const int cl = cb2 + j * 4;
    if (hw0 + hi < HW)
      xo[((size_t)(b * CC + c0 + cl)) * HW + hw0 + hi] = T[cl][hi];
  }
}

// ---------------------------------------------------------------------------
extern "C" void kernel_launch(void* const* d_in, const int* in_sizes, int n_in,
                              void* d_out, int out_size, void* d_ws, size_t ws_size,
                              hipStream_t stream) {
  const float* cls    = (const float*)d_in[0];
  const float* x      = (const float*)d_in[1];
  const float* conv_w = (const float*)d_in[2];
  const float* conv_b = (const float*)d_in[3];
  const float* ln1_g  = (const float*)d_in[4];
  const float* ln1_b  = (const float*)d_in[5];
  const float* qkv_w  = (const float*)d_in[6];
  const float* proj_w = (const float*)d_in[7];
  const float* proj_b = (const float*)d_in[8];
  const float* ln2_g  = (const float*)d_in[9];
  const float* ln2_b  = (const float*)d_in[10];
  const float* fc1_w  = (const float*)d_in[11];
  const float* fc1_b  = (const float*)d_in[12];
  const float* fc2_w  = (const float*)d_in[13];
  const float* fc2_b  = (const float*)d_in[14];

  float* outf = (float*)d_out;
  float* ga = outf + (size_t)CB * CC + (size_t)CB * CC * HW;
  // vt scratch lives in the (not-yet-written) x_out region of d_out
  short* vtb = (short*)(outf + CB * CC);

  char* ws = (char*)d_ws;
  float* xc   = (float*)ws;
  short* y    = (short*)(ws + 19292160ULL);
  short* qkvb = (short*)(ws + 28938240ULL);
  short* o    = (short*)(ws + 57876480ULL);
  short* m1   = (short*)(ws + 28938240ULL);
  short* wbuf = (short*)(ws + 67522560ULL);
  short* qkv_wb = wbuf;
  short* proj_wb = wbuf + 442368;
  short* fc1_wb  = wbuf + 589824;
  short* fc2_wb  = wbuf + 1179648;

  const int thr = 256;
  k_misc<<<49, thr, 0, stream>>>(cls, xc, ga);
  k_wconv<<<1728, thr, 0, stream>>>(qkv_w, proj_w, fc1_w, fc2_w, wbuf);
  k_conv_t<<<dim3(13, 6, CB), thr, 0, stream>>>(x, conv_w, conv_b, xc);
  k_ln<<<CM / 4, thr, 0, stream>>>(xc, ln1_g, ln1_b, y, CM);
  k_gemm<128, 0, 0, 0, 1><<<99 * 9, thr, 0, stream>>>(
      y, qkv_wb, nullptr, nullptr, qkvb, CM, C3, CC, 9);
  k_vt<<<dim3(13, CB * 8), thr, 0, stream>>>(qkvb, vtb);
  k_attn<<<1664, thr, 0, stream>>>(qkvb, vtb, o);
  k_gattn<<<CB * 8, thr, 0, stream>>>(qkvb, ga);
  k_gemm<64, 0, 1, 1, 0><<<197 * 3, thr, 0, stream>>>(
      o, proj_wb, proj_b, xc, xc, CM, CC, CC, 3);
  k_ln<<<CM / 4, thr, 0, stream>>>(xc, ln2_g, ln2_b, y, CM);
  k_gemm<128, 1, 0, 1, 1><<<99 * 12, thr, 0, stream>>>(
      y, fc1_wb, fc1_b, nullptr, m1, CM, CF, CC, 12);
  k_gemm<64, 0, 1, 1, 0><<<197 * 3, thr, 0, stream>>>(
      m1, fc2_wb, fc2_b, xc, xc, CM, CC, CF, 3);
  k_out<<<dim3(79, CB), thr, 0, stream>>>(xc, outf);
}

// Round 14
// 334.826 us; speedup vs baseline: 1.0040x; 1.0040x over previous
//
#include <hip/hip_runtime.h>
#include <hip/hip_bf16.h>

#define DI __device__ __forceinline__

typedef __attribute__((ext_vector_type(4))) float f32x4;
typedef __attribute__((ext_vector_type(8))) short bf16x8;
typedef __attribute__((ext_vector_type(4))) short bf16x4;

static constexpr int CB = 16;        // batch
static constexpr int CC = 384;       // channels
static constexpr int CH = 28, CW = 28;
static constexpr int CD = 48;        // head dim
static constexpr int CN = 785;       // 1 + 28*28
static constexpr int CM = CB * CN;   // 12560 rows
static constexpr int C3 = 3 * CC;    // 1152
static constexpr int CF = 4 * CC;    // 1536
static constexpr int HW = CH * CW;   // 784
static constexpr int NP = 832;       // padded seq for vt

DI short f2b(float f) {
  __hip_bfloat16 h = __float2bfloat16(f);
  return *reinterpret_cast<short*>(&h);
}
DI float b2f(short s) {
  union { unsigned u; float f; } x;
  x.u = ((unsigned)(unsigned short)s) << 16;
  return x.f;
}

DI void gload16(const short* g, short* l) {
  __builtin_amdgcn_global_load_lds((const __attribute__((address_space(1))) void*)g,
                                   (__attribute__((address_space(3))) void*)l, 16, 0, 0);
}

// ---------------------------------------------------------------------------
// K0b: convert weights fp32 -> bf16; also zero global_attn + write cls row
//      (fused k_misc: grid 1728 covers both)
// ---------------------------------------------------------------------------
__global__ void k_wconv(const float* __restrict__ s0, const float* __restrict__ s1,
                        const float* __restrict__ s2, const float* __restrict__ s3,
                        short* __restrict__ dst,
                        const float* __restrict__ cls, float* __restrict__ xc,
                        float* __restrict__ ga) {
  const int gid0 = blockIdx.x * 256 + threadIdx.x;
  if (gid0 < CB * HW) ga[gid0] = 0.f;
  if (gid0 < CB * CC) {
    const int b = gid0 / CC, c = gid0 % CC;
    xc[((size_t)b * CN) * CC + c] = cls[gid0];
  }
  const int gid = gid0 * 4;
  if (gid >= 1769472) return;
  const float* s; int off;
  if (gid < 442368)       { s = s0; off = gid; }
  else if (gid < 589824)  { s = s1; off = gid - 442368; }
  else if (gid < 1179648) { s = s2; off = gid - 589824; }
  else                    { s = s3; off = gid - 1179648; }
  f32x4 v = *(const f32x4*)(s + off);
  bf16x4 o;
#pragma unroll
  for (int i = 0; i < 4; i++) o[i] = f2b(v[i]);
  *(bf16x4*)(dst + gid) = o;
}

// ---------------------------------------------------------------------------
// K1: depthwise conv3x3 + residual, coalesced along hw, LDS-transposed write.
// ---------------------------------------------------------------------------
__global__ __launch_bounds__(256) void k_conv_t(const float* __restrict__ x,
                                                const float* __restrict__ cw,
                                                const float* __restrict__ cb,
                                                float* __restrict__ xc) {
  __shared__ float T[64][65];
  __shared__ float Wc[64 * 9];
  __shared__ float Cbs[64];
  const int b = blockIdx.z;
  const int cc = blockIdx.y * 64;
  const int hw0 = blockIdx.x * 64;
  const int t = threadIdx.x;
  const int hwi = t & 63, ci0 = t >> 6;
  const int hw = hw0 + hwi;
  const int yy = hw / CW, xx = hw % CW;
  const int ci2 = t & 63, hb2 = t >> 6;

  for (int i = t; i < 64 * 9; i += 256) Wc[i] = cw[cc * 9 + i];
  if (t < 64) Cbs[t] = cb[cc + t];
  __syncthreads();
  if (hw < HW) {
    const int ctr = yy * CW + xx;
    int off9[9]; float mk9[9];
#pragma unroll
    for (int ky = 0; ky < 3; ky++)
#pragma unroll
      for (int kx = 0; kx < 3; kx++) {
        const int iy = yy + ky - 1, ix = xx + kx - 1;
        const bool v = (iy >= 0 && iy < CH && ix >= 0 && ix < CW);
        off9[ky * 3 + kx] = v ? iy * CW + ix : ctr;
        mk9[ky * 3 + kx] = v ? 1.f : 0.f;
      }
#pragma unroll
    for (int j = 0; j < 16; j += 2) {
      const int cl0 = ci0 * 16 + j;
      const float* xp0 = x + ((size_t)(b * CC + cc + cl0)) * HW;
      const float* xp1 = xp0 + HW;
      float t0[9], t1[9];
#pragma unroll
      for (int q = 0; q < 9; q++) { t0[q] = xp0[off9[q]]; t1[q] = xp1[off9[q]]; }
      const float c0 = xp0[ctr], c1 = xp1[ctr];
      float a0 = Cbs[cl0], a1 = Cbs[cl0 + 1];
#pragma unroll
      for (int q = 0; q < 9; q++) {
        a0 += Wc[cl0 * 9 + q] * (t0[q] * mk9[q]);
        a1 += Wc[(cl0 + 1) * 9 + q] * (t1[q] * mk9[q]);
      }
      T[cl0][hwi] = c0 + a0;
      T[cl0 + 1][hwi] = c1 + a1;
    }
  }
  __syncthreads();
#pragma unroll
  for (int j = 0; j < 16; j++) {
    const int hwl = hb2 + j * 4;
    if (hw0 + hwl < HW)
      xc[((size_t)b * CN + 1 + hw0 + hwl) * CC + cc + ci2] = T[ci2][hwl];
  }
}

// ---------------------------------------------------------------------------
// K2: LayerNorm over last dim (384), fp32 in -> bf16 out. 1 wave per row.
// ---------------------------------------------------------------------------
__global__ __launch_bounds__(256) void k_ln(const float* __restrict__ xin,
                                            const float* __restrict__ g,
                                            const float* __restrict__ bta,
                                            short* __restrict__ y, int Mtot) {
  const int row = blockIdx.x * 4 + (threadIdx.x >> 6);
  const int l = threadIdx.x & 63;
  if (row >= Mtot) return;
  const float* xr = xin + (size_t)row * CC;
  float v[6], s = 0.f, ss = 0.f;
#pragma unroll
  for (int i = 0; i < 6; i++) {
    v[i] = xr[l + i * 64];
    s += v[i];
    ss += v[i] * v[i];
  }
#pragma unroll
  for (int m = 1; m < 64; m <<= 1) { s += __shfl_xor(s, m); ss += __shfl_xor(ss, m); }
  const float mu = s * (1.f / CC);
  const float var = ss * (1.f / CC) - mu * mu;
  const float r = rsqrtf(var + 1e-5f);
#pragma unroll
  for (int i = 0; i < 6; i++) {
    const int c = l + i * 64;
    y[(size_t)row * CC + c] = f2b((v[i] - mu) * r * g[c] + bta[c]);
  }
}

// ---------------------------------------------------------------------------
// K3: GEMM  C[M,N] = A[M,K] @ W[N,K]^T (+bias)(+gelu)(+resid)
//     2-buffer pipelined + XCD-chunked N-fastest grid swizzle (round-12 best).
// ---------------------------------------------------------------------------
template <int BM, int DOGELU, int DORES, int DOBIAS, int OUTBF>
__global__ __launch_bounds__(256) void k_gemm(const short* __restrict__ A,
                                              const short* __restrict__ W,
                                              const float* __restrict__ bias,
                                              const float* __restrict__ resid,
                                              void* __restrict__ out_,
                                              int M, int N, int K, int NN) {
  constexpr int MI = BM / 32;
  constexpr int ACALLS = BM / 64;
  constexpr int ASZ = BM * 32, BSZ = 128 * 32;
  __shared__ short As[2 * ASZ];
  __shared__ short Bs[2 * BSZ];

  const int nwg = gridDim.x;
  const int q = nwg >> 3, r = nwg & 7;
  const int x = blockIdx.x & 7, j = blockIdx.x >> 3;
  const int base = (x < r) ? x * (q + 1) : r * (q + 1) + (x - r) * q;
  const int wgid = base + j;
  const int bm = (wgid / NN) * BM, bn = (wgid % NN) * 128;

  const int t = threadIdx.x, w = t >> 6, l = t & 63, g = l >> 4, li = l & 15;
  const int wm = (w >> 1) * (BM / 2), wn = (w & 1) * 64;

  const int srow = l >> 2;
  const int scol = (l & 3) * 8;
  const short* aSrc[ACALLS]; int aOff[ACALLS];
#pragma unroll
  for (int jj = 0; jj < ACALLS; jj++) {
    int arow = bm + w * (BM / 4) + jj * 16 + srow; if (arow > M - 1) arow = M - 1;
    aSrc[jj] = A + (size_t)arow * K + scol;
    aOff[jj] = (w * (BM / 4) + jj * 16) * 32;
  }
  const short* bSrc[2]; int bOff[2];
#pragma unroll
  for (int jj = 0; jj < 2; jj++) {
    const int brow = bn + w * 32 + jj * 16 + srow;
    bSrc[jj] = W + (size_t)brow * K + scol;
    bOff[jj] = (w * 32 + jj * 16) * 32;
  }

  auto stage = [&](int buf, int kt) {
    const int ko = kt * 32;
#pragma unroll
    for (int jj = 0; jj < ACALLS; jj++)
      gload16(aSrc[jj] + ko, &As[buf * ASZ] + aOff[jj]);
#pragma unroll
    for (int jj = 0; jj < 2; jj++)
      gload16(bSrc[jj] + ko, &Bs[buf * BSZ] + bOff[jj]);
  };

  f32x4 acc[MI][4] = {};
  const int nkt = K / 32;
  stage(0, 0);
  __syncthreads();
  int cur = 0;
  for (int kt = 0; kt < nkt; kt++) {
    if (kt + 1 < nkt) stage(cur ^ 1, kt + 1);
    const short* Ab = &As[cur * ASZ];
    const short* Bb = &Bs[cur * BSZ];
    bf16x8 af[MI], bf[4];
#pragma unroll
    for (int mi = 0; mi < MI; mi++)
      af[mi] = *(const bf16x8*)&Ab[(wm + mi * 16 + li) * 32 + g * 8];
#pragma unroll
    for (int ni = 0; ni < 4; ni++)
      bf[ni] = *(const bf16x8*)&Bb[(wn + ni * 16 + li) * 32 + g * 8];
#pragma unroll
    for (int mi = 0; mi < MI; mi++)
#pragma unroll
      for (int ni = 0; ni < 4; ni++)
        acc[mi][ni] = __builtin_amdgcn_mfma_f32_16x16x32_bf16(af[mi], bf[ni], acc[mi][ni], 0, 0, 0);
    __syncthreads();
    cur ^= 1;
  }

#pragma unroll
  for (int mi = 0; mi < MI; mi++)
#pragma unroll
    for (int ni = 0; ni < 4; ni++) {
      const int col = bn + wn + ni * 16 + li;
      float bv = 0.f;
      if constexpr (DOBIAS) bv = bias[col];
#pragma unroll
      for (int rr = 0; rr < 4; rr++) {
        const int row = bm + wm + mi * 16 + g * 4 + rr;
        if (row < M) {
          float v = acc[mi][ni][rr] + bv;
          if constexpr (DOGELU) v = 0.5f * v * (1.f + erff(v * 0.7071067811865475f));
          if constexpr (DORES) v += resid[(size_t)row * N + col];
          if constexpr (OUTBF)
            ((short*)out_)[(size_t)row * N + col] = f2b(v);
          else
            ((float*)out_)[(size_t)row * N + col] = v;
        }
      }
    }
}

// ---------------------------------------------------------------------------
// K3b: pre-transpose V: qkvb[b][n][768 + h*48 + d] -> vt[bh][d][NP=832]
// ---------------------------------------------------------------------------
__global__ __launch_bounds__(256) void k_vt(const short* __restrict__ qkv,
                                            short* __restrict__ vt) {
  __shared__ short Tl[48 * 71];
  const int n0 = blockIdx.x * 64;
  const int bh = blockIdx.y;
  const int b = bh >> 3, h = bh & 7;
  const int t = threadIdx.x;
  const size_t bbase = (size_t)b * CN;
#pragma unroll
  for (int it = 0; it < 2; it++) {
    const int gi = t + it * 256;
    if (gi < 384) {
      const int nrel = gi / 6, dg = gi % 6;
      const int n = n0 + nrel;
      bf16x8 val = {};
      if (n < CN)
        val = *(const bf16x8*)(qkv + (bbase + n) * C3 + 2 * CC + h * CD + dg * 8);
#pragma unroll
      for (int i = 0; i < 8; i++) Tl[(dg * 8 + i) * 71 + nrel] = val[i];
    }
  }
  __syncthreads();
#pragma unroll
  for (int it = 0; it < 2; it++) {
    const int gj = t + it * 256;
    if (gj < 384) {
      const int d = gj >> 3, ng = gj & 7;
      bf16x8 v;
#pragma unroll
      for (int i = 0; i < 8; i++) v[i] = Tl[d * 71 + ng * 8 + i];
      *(bf16x8*)(vt + ((size_t)bh * CD + d) * NP + n0 + ng * 8) = v;
    }
  }
}

// ---------------------------------------------------------------------------
// K4: flash attention — round-12 structure (12KB LDS, 1-tile reg prefetch,
//     two __syncthreads/tile; measured 53.6us) + occupancy-neutral VALU cuts:
//     Q pre-scaled by scale*log2e -> exp2 softmax; OOB mask hoisted to last
//     tile; defer-max (THR=8 log2) makes rescale+shfl chain conditional.
// ---------------------------------------------------------------------------
__global__ __launch_bounds__(256) void k_attn(const short* __restrict__ qkv,
                                              const short* __restrict__ vt,
                                              short* __restrict__ o) {
  __shared__ short Ks[64 * 48];   // [kv][d] rows 96B, XOR-swizzled
  __shared__ short Vs[48 * 64];   // [d][kv] rows 128B, XOR-swizzled
  const int f = blockIdx.x;
  const int xslot = f & 7, grp = f >> 3;
  const int bh = xslot + 8 * (grp & 15);
  const int qt = grp >> 4;                 // 0..12
  const int b = bh >> 3, h = bh & 7;
  const int q0 = qt * 64;
  const int t = threadIdx.x, w = t >> 6, l = t & 63, g = l >> 4, li = l & 15;
  const size_t bbase = (size_t)b * CN;

  // Q fragment pre-scaled by 1/sqrt(48)*log2(e): softmax becomes exp2
  const float SC = 0.14433756729740643f * 1.4426950408889634f;
  const int qrow = q0 + w * 16 + li;
  const int qr = qrow > CN - 1 ? CN - 1 : qrow;
  const short* qb = qkv + (bbase + qr) * C3 + h * CD;
  bf16x8 qf0, qf1 = {};
  {
    bf16x8 q0r = *(const bf16x8*)(qb + g * 8);
#pragma unroll
    for (int i = 0; i < 8; i++) qf0[i] = f2b(b2f(q0r[i]) * SC);
    if (g < 2) {
      bf16x8 q1r = *(const bf16x8*)(qb + 32 + g * 8);
#pragma unroll
      for (int i = 0; i < 8; i++) qf1[i] = f2b(b2f(q1r[i]) * SC);
    }
  }

  float mr = -1e30f, ls = 0.f;
  f32x4 oa[3] = {};

  const int krow0 = t / 6, kcg0 = t % 6;
  const int krow1 = (t + 256) / 6, kcg1 = (t + 256) % 6;   // valid when t<128
  const int vd0 = t >> 3, vkvg0 = t & 7;
  const int vd1 = (t + 256) >> 3, vkvg1 = (t + 256) & 7;   // valid when t<128
  const short* kbase = qkv + bbase * C3 + CC + h * CD;
  const short* vbase = vt + (size_t)bh * CD * NP;

  bf16x8 kr0 = {}, kr1 = {}, vr0 = {}, vr1 = {};
  kr0 = *(const bf16x8*)(kbase + (size_t)min(krow0, CN - 1) * C3 + kcg0 * 8);
  vr0 = *(const bf16x8*)(vbase + vd0 * NP + vkvg0 * 8);
  if (t < 128) {
    kr1 = *(const bf16x8*)(kbase + (size_t)min(krow1, CN - 1) * C3 + kcg1 * 8);
    vr1 = *(const bf16x8*)(vbase + vd1 * NP + vkvg1 * 8);
  }

  for (int kt = 0; kt < 13; kt++) {
    const int kv0 = kt * 64;
    __syncthreads();   // previous compute done; LDS free
    *(bf16x8*)((char*)Ks + ((krow0 * 96 + kcg0 * 16) ^ ((krow0 & 7) << 4))) = kr0;
    *(bf16x8*)((char*)Vs + ((vd0 * 128 + vkvg0 * 16) ^ ((vd0 & 7) << 4))) = vr0;
    if (t < 128) {
      *(bf16x8*)((char*)Ks + ((krow1 * 96 + kcg1 * 16) ^ ((krow1 & 7) << 4))) = kr1;
      *(bf16x8*)((char*)Vs + ((vd1 * 128 + vkvg1 * 16) ^ ((vd1 & 7) << 4))) = vr1;
    }
    __syncthreads();   // LDS ready
    if (kt < 12) {     // issue next-tile loads early; latency hides under MFMA
      const int kn = kv0 + 64;
      kr0 = *(const bf16x8*)(kbase + (size_t)min(kn + krow0, CN - 1) * C3 + kcg0 * 8);
      vr0 = *(const bf16x8*)(vbase + vd0 * NP + kn + vkvg0 * 8);
      if (t < 128) {
        kr1 = *(const bf16x8*)(kbase + (size_t)min(kn + krow1, CN - 1) * C3 + kcg1 * 8);
        vr1 = *(const bf16x8*)(vbase + vd1 * NP + kn + vkvg1 * 8);
      }
    }

    // ---- S = K Q^T (pre-scaled, log2 domain)
    f32x4 s[4];
    __builtin_amdgcn_s_setprio(1);
#pragma unroll
    for (int ni = 0; ni < 4; ni++) {
      const int krw = ni * 16 + li;
      const int sw = (krw & 7) << 4;
      bf16x8 kf0 = *(const bf16x8*)((char*)Ks + ((krw * 96 + g * 16) ^ sw));
      bf16x8 kf1 = {};
      if (g < 2) kf1 = *(const bf16x8*)((char*)Ks + ((krw * 96 + 64 + g * 16) ^ sw));
      f32x4 acc = {};
      acc = __builtin_amdgcn_mfma_f32_16x16x32_bf16(kf0, qf0, acc, 0, 0, 0);
      acc = __builtin_amdgcn_mfma_f32_16x16x32_bf16(kf1, qf1, acc, 0, 0, 0);
      s[ni] = acc;
    }
    __builtin_amdgcn_s_setprio(0);

    // OOB mask only on the last tile (kv 768..831; valid < 785)
    if (kt == 12) {
#pragma unroll
      for (int ni = 0; ni < 4; ni++)
#pragma unroll
        for (int rr = 0; rr < 4; rr++)
          if (768 + ni * 16 + g * 4 + rr >= CN) s[ni][rr] = -1e30f;
    }

    // row max across the 16 per-lane elems, then across g (2 shfl_xor)
    float mt = s[0][0];
#pragma unroll
    for (int ni = 0; ni < 4; ni++)
#pragma unroll
      for (int rr = 0; rr < 4; rr++) mt = fmaxf(mt, s[ni][rr]);
    mt = fmaxf(mt, __shfl_xor(mt, 16));
    mt = fmaxf(mt, __shfl_xor(mt, 32));

    // defer-max: rescale only if some row grew > 8 (log2 units)
    if (!__all(mt - mr <= 8.f)) {
      const float mn = fmaxf(mr, mt);
      const float al = __builtin_exp2f(mr - mn);
      mr = mn;
      ls *= al;
      const int sb = (l & 48) + ((l & 48) >> 2);
      float ar[4];
#pragma unroll
      for (int rr = 0; rr < 4; rr++) ar[rr] = __shfl(al, sb + rr);
#pragma unroll
      for (int d = 0; d < 3; d++)
#pragma unroll
        for (int rr = 0; rr < 4; rr++) oa[d][rr] *= ar[rr];
    }

    float ps = 0.f;
#pragma unroll
    for (int ni = 0; ni < 4; ni++)
#pragma unroll
      for (int rr = 0; rr < 4; rr++) {
        const float p = __builtin_exp2f(s[ni][rr] - mr);
        s[ni][rr] = p;
        ps += p;
      }
    ps += __shfl_xor(ps, 16);
    ps += __shfl_xor(ps, 32);
    ls += ps;

    // pack P per sigma: k=g*8+i -> kv = ks*32 + (i<4 ? g*4+i : 16+g*4+i-4)
    bf16x8 pa[2];
#pragma unroll
    for (int ks = 0; ks < 2; ks++)
#pragma unroll
      for (int i = 0; i < 8; i++)
        pa[ks][i] = f2b(i < 4 ? s[2 * ks][i] : s[2 * ks + 1][i - 4]);

    // O += P V
    __builtin_amdgcn_s_setprio(1);
#pragma unroll
    for (int d = 0; d < 3; d++) {
      const int drow = d * 16 + li;
      const int sw = (drow & 7) << 4;
#pragma unroll
      for (int ks = 0; ks < 2; ks++) {
        bf16x4 lo = *(const bf16x4*)((char*)Vs + ((drow * 128 + ks * 64 + g * 8) ^ sw));
        bf16x4 hi = *(const bf16x4*)((char*)Vs + ((drow * 128 + ks * 64 + 32 + g * 8) ^ sw));
        bf16x8 vb;
#pragma unroll
        for (int i = 0; i < 4; i++) { vb[i] = lo[i]; vb[4 + i] = hi[i]; }
        oa[d] = __builtin_amdgcn_mfma_f32_16x16x32_bf16(pa[ks], vb, oa[d], 0, 0, 0);
      }
    }
    __builtin_amdgcn_s_setprio(0);
  }

  // epilogue: O[q=g*4+r][d=d*16+li]; ls lives at lane li=q -> shfl
  const int sb = (l & 48) + ((l & 48) >> 2);
  float lr[4];
#pragma unroll
  for (int rr = 0; rr < 4; rr++) lr[rr] = __shfl(ls, sb + rr);
#pragma unroll
  for (int d = 0; d < 3; d++)
#pragma unroll
    for (int rr = 0; rr < 4; rr++) {
      const int n = q0 + w * 16 + g * 4 + rr;
      if (n < CN)
        o[(bbase + n) * CC + h * CD + d * 16 + li] = f2b(oa[d][rr] / lr[rr]);
    }
}

// ---------------------------------------------------------------------------
// K5: global_attn = mean over heads of softmax(q0 . k)[1:]. grid = B*H blocks.
// ---------------------------------------------------------------------------
__global__ __launch_bounds__(256) void k_gattn(const short* __restrict__ qkv,
                                               float* __restrict__ ga) {
  const int b = blockIdx.x >> 3, h = blockIdx.x & 7;
  __shared__ float red[4];
  const int t = threadIdx.x;
  const size_t bbase = (size_t)b * CN;
  const short* q0 = qkv + bbase * C3 + h * CD;
  float qv[CD];
#pragma unroll
  for (int i = 0; i < CD; i++) qv[i] = b2f(q0[i]);
  float lg[4], ev[4];
  float lmax = -1e30f;
#pragma unroll
  for (int j = 0; j < 4; j++) {
    const int m = t + j * 256;
    if (m < CN) {
      const short* kr = qkv + (bbase + m) * C3 + CC + h * CD;
      float acc = 0.f;
#pragma unroll
      for (int i = 0; i < CD; i++) acc += qv[i] * b2f(kr[i]);
      lg[j] = acc * 0.14433756729740643f;
      lmax = fmaxf(lmax, lg[j]);
    } else lg[j] = -1e30f;
  }
  for (int msk = 1; msk < 64; msk <<= 1) lmax = fmaxf(lmax, __shfl_xor(lmax, msk));
  if ((t & 63) == 0) red[t >> 6] = lmax;
  __syncthreads();
  lmax = fmaxf(fmaxf(red[0], red[1]), fmaxf(red[2], red[3]));
  __syncthreads();
  float es = 0.f;
#pragma unroll
  for (int j = 0; j < 4; j++) {
    ev[j] = (t + j * 256 < CN) ? __expf(lg[j] - lmax) : 0.f;
    es += ev[j];
  }
  for (int msk = 1; msk < 64; msk <<= 1) es += __shfl_xor(es, msk);
  if ((t & 63) == 0) red[t >> 6] = es;
  __syncthreads();
  es = red[0] + red[1] + red[2] + red[3];
  const float inv = 0.125f / es;
#pragma unroll
  for (int j = 0; j < 4; j++) {
    const int m = t + j * 256;
    if (m >= 1 && m < CN) atomicAdd(&ga[b * HW + m - 1], ev[j] * inv);
  }
}

// ---------------------------------------------------------------------------
// K6: output: x_out via LDS-tiled transpose (both sides coalesced) + cls_out
// ---------------------------------------------------------------------------
__global__ __launch_bounds__(256) void k_out(const float* __restrict__ xc,
                                             float* __restrict__ outp) {
  const int b = blockIdx.y, tile = blockIdx.x, t = threadIdx.x;
  if (tile == 78) {
    for (int i = t; i < CC; i += 256)
      outp[b * CC + i] = xc[((size_t)b * CN) * CC + i];
    return;
  }
  __shared__ float T[64][65];
  const int ct = tile / 13, ht = tile % 13;
  const int c0 = ct * 64, hw0 = ht * 64;
  const int ci = t & 63, hb = t >> 6;
  for (int j = 0; j < 16; j++) {
    const int hwl = hb + j * 4;
    if (hw0 + hwl < HW)
      T[ci][hwl] = xc[((size_t)b * CN + 1 + hw0 + hwl) * CC + c0 + ci];
  }
  __syncthreads();
  const int hi = t & 63, cb2 = t >> 6;
  float* xo = outp + CB * CC;
  for (int j = 0; j < 16; j++) {
    const int cl = cb2 + j * 4;
    if (hw0 + hi < HW)
      xo[((size_t)(b * CC + c0 + cl)) * HW + hw0 + hi] = T[cl][hi];
  }
}

// ---------------------------------------------------------------------------
extern "C" void kernel_launch(void* const* d_in, const int* in_sizes, int n_in,
                              void* d_out, int out_size, void* d_ws, size_t ws_size,
                              hipStream_t stream) {
  const float* cls    = (const float*)d_in[0];
  const float* x      = (const float*)d_in[1];
  const float* conv_w = (const float*)d_in[2];
  const float* conv_b = (const float*)d_in[3];
  const float* ln1_g  = (const float*)d_in[4];
  const float* ln1_b  = (const float*)d_in[5];
  const float* qkv_w  = (const float*)d_in[6];
  const float* proj_w = (const float*)d_in[7];
  const float* proj_b = (const float*)d_in[8];
  const float* ln2_g  = (const float*)d_in[9];
  const float* ln2_b  = (const float*)d_in[10];
  const float* fc1_w  = (const float*)d_in[11];
  const float* fc1_b  = (const float*)d_in[12];
  const float* fc2_w  = (const float*)d_in[13];
  const float* fc2_b  = (const float*)d_in[14];

  float* outf = (float*)d_out;
  float* ga = outf + (size_t)CB * CC + (size_t)CB * CC * HW;
  // vt scratch lives in the (not-yet-written) x_out region of d_out
  short* vtb = (short*)(outf + CB * CC);

  char* ws = (char*)d_ws;
  float* xc   = (float*)ws;
  short* y    = (short*)(ws + 19292160ULL);
  short* qkvb = (short*)(ws + 28938240ULL);
  short* o    = (short*)(ws + 57876480ULL);
  short* m1   = (short*)(ws + 28938240ULL);
  short* wbuf = (short*)(ws + 67522560ULL);
  short* qkv_wb = wbuf;
  short* proj_wb = wbuf + 442368;
  short* fc1_wb  = wbuf + 589824;
  short* fc2_wb  = wbuf + 1179648;

  const int thr = 256;
  k_wconv<<<1728, thr, 0, stream>>>(qkv_w, proj_w, fc1_w, fc2_w, wbuf, cls, xc, ga);
  k_conv_t<<<dim3(13, 6, CB), thr, 0, stream>>>(x, conv_w, conv_b, xc);
  k_ln<<<CM / 4, thr, 0, stream>>>(xc, ln1_g, ln1_b, y, CM);
  k_gemm<128, 0, 0, 0, 1><<<99 * 9, thr, 0, stream>>>(
      y, qkv_wb, nullptr, nullptr, qkvb, CM, C3, CC, 9);
  k_vt<<<dim3(13, CB * 8), thr, 0, stream>>>(qkvb, vtb);
  k_attn<<<1664, thr, 0, stream>>>(qkvb, vtb, o);
  k_gattn<<<CB * 8, thr, 0, stream>>>(qkvb, ga);
  k_gemm<64, 0, 1, 1, 0><<<197 * 3, thr, 0, stream>>>(
      o, proj_wb, proj_b, xc, xc, CM, CC, CC, 3);
  k_ln<<<CM / 4, thr, 0, stream>>>(xc, ln2_g, ln2_b, y, CM);
  k_gemm<128, 1, 0, 1, 1><<<99 * 12, thr, 0, stream>>>(
      y, fc1_wb, fc1_b, nullptr, m1, CM, CF, CC, 12);
  k_gemm<64, 0, 1, 1, 0><<<197 * 3, thr, 0, stream>>>(
      m1, fc2_wb, fc2_b, xc, xc, CM, CC, CF, 3);
  k_out<<<dim3(79, CB), thr, 0, stream>>>(xc, outf);
}